// Round 1
// baseline (330.620 us; speedup 1.0000x reference)
//
#include <hip/hip_runtime.h>
#include <hip/hip_bf16.h>

typedef short bf16x8 __attribute__((ext_vector_type(8)));
typedef float f32x4  __attribute__((ext_vector_type(4)));

#define LSEQ 2048
#define DDIM 512
#define NBAT 8

// ---------------- convert x fp32 -> bf16 ----------------
__global__ void k_cvt_x(const float* __restrict__ x, __hip_bfloat16* __restrict__ xb) {
    size_t i = ((size_t)blockIdx.x * 256 + threadIdx.x) * 4;
    float4 v = *(const float4*)(x + i);
    __hip_bfloat16 h[4] = { __float2bfloat16(v.x), __float2bfloat16(v.y),
                            __float2bfloat16(v.z), __float2bfloat16(v.w) };
    *(short4*)(xb + i) = *(short4*)h;
}

// ---------------- convert + transpose weights ----------------
// Wt[n][k] = W[k][n], bf16.  4 matrices: q,k,v -> Wtqkv rows [mat*512..), o -> Wto
__global__ void k_cvt_w(const float* __restrict__ Wq, const float* __restrict__ Wk,
                        const float* __restrict__ Wv, const float* __restrict__ Wo,
                        __hip_bfloat16* __restrict__ Wtqkv, __hip_bfloat16* __restrict__ Wto) {
    __shared__ float t[32][33];
    int mat = blockIdx.x >> 8;
    int tb  = blockIdx.x & 255;
    int tk  = tb >> 4, tn = tb & 15;
    const float* W = (mat == 0) ? Wq : (mat == 1) ? Wk : (mat == 2) ? Wv : Wo;
    int c  = threadIdx.x & 31;
    int r0 = threadIdx.x >> 5;
#pragma unroll
    for (int i = 0; i < 4; ++i) {
        int r = r0 + i * 8;
        t[r][c] = W[(size_t)(tk * 32 + r) * 512 + tn * 32 + c];
    }
    __syncthreads();
    __hip_bfloat16* dst = (mat < 3) ? (Wtqkv + (size_t)mat * 512 * 512) : Wto;
#pragma unroll
    for (int i = 0; i < 4; ++i) {
        int n = r0 + i * 8;
        dst[(size_t)(tn * 32 + n) * 512 + tk * 32 + c] = __float2bfloat16(t[c][n]);
    }
}

// ---------------- fused QKV GEMM: C = xb @ [Wq|Wk|Wv]  (Bt form) ----------------
// writes Q [16384][512], K [16384][512], Vt [8][512][2048]
__global__ __launch_bounds__(256, 2)
void k_gemm_qkv(const __hip_bfloat16* __restrict__ A, const __hip_bfloat16* __restrict__ Bt,
                __hip_bfloat16* __restrict__ Q, __hip_bfloat16* __restrict__ Kb,
                __hip_bfloat16* __restrict__ Vt) {
    __shared__ char As[8192], Bs[8192];
    const int tid = threadIdx.x, lane = tid & 63, w = tid >> 6;
    const int l15 = lane & 15, l4 = lane >> 4;
    const int mt = blockIdx.x, nt = blockIdx.y;
    const int wr = (w >> 1) * 64, wc = (w & 1) * 64;
    f32x4 acc[4][4] = {};
    const int c0 = tid, c1 = tid + 256;
    const int r0 = c0 >> 2, o0 = c0 & 3, r1 = c1 >> 2, o1 = c1 & 3;

#pragma unroll 1
    for (int kt = 0; kt < 16; ++kt) {
        __syncthreads();
        bf16x8 a0 = *(const bf16x8*)(A + (size_t)(mt * 128 + r0) * 512 + kt * 32 + o0 * 8);
        bf16x8 a1 = *(const bf16x8*)(A + (size_t)(mt * 128 + r1) * 512 + kt * 32 + o1 * 8);
        bf16x8 b0 = *(const bf16x8*)(Bt + (size_t)(nt * 128 + r0) * 512 + kt * 32 + o0 * 8);
        bf16x8 b1 = *(const bf16x8*)(Bt + (size_t)(nt * 128 + r1) * 512 + kt * 32 + o1 * 8);
        *(bf16x8*)(As + r0 * 64 + ((o0 * 16) ^ ((((r0 >> 1) & 3)) << 4))) = a0;
        *(bf16x8*)(As + r1 * 64 + ((o1 * 16) ^ ((((r1 >> 1) & 3)) << 4))) = a1;
        *(bf16x8*)(Bs + r0 * 64 + ((o0 * 16) ^ ((((r0 >> 1) & 3)) << 4))) = b0;
        *(bf16x8*)(Bs + r1 * 64 + ((o1 * 16) ^ ((((r1 >> 1) & 3)) << 4))) = b1;
        __syncthreads();
        bf16x8 af[4], bfr[4];
#pragma unroll
        for (int i = 0; i < 4; ++i) {
            int r = wr + 16 * i + l15;
            af[i] = *(const bf16x8*)(As + r * 64 + ((16 * l4) ^ ((((r >> 1) & 3)) << 4)));
        }
#pragma unroll
        for (int j = 0; j < 4; ++j) {
            int r = wc + 16 * j + l15;
            bfr[j] = *(const bf16x8*)(Bs + r * 64 + ((16 * l4) ^ ((((r >> 1) & 3)) << 4)));
        }
#pragma unroll
        for (int i = 0; i < 4; ++i)
#pragma unroll
            for (int j = 0; j < 4; ++j)
                acc[i][j] = __builtin_amdgcn_mfma_f32_16x16x32_bf16(af[i], bfr[j], acc[i][j], 0, 0, 0);
    }
    // epilogue: route to Q / K / Vt
    const int which = (nt * 128) >> 9;  // uniform per block (0=q,1=k,2=v)
#pragma unroll
    for (int i = 0; i < 4; ++i) {
#pragma unroll
        for (int r = 0; r < 4; ++r) {
            int grow = mt * 128 + wr + 16 * i + (l4 << 2) + r;
#pragma unroll
            for (int j = 0; j < 4; ++j) {
                int gcol = nt * 128 + wc + 16 * j + l15;
                int cc = gcol & 511;
                __hip_bfloat16 h = __float2bfloat16(acc[i][j][r]);
                if (which == 0)      Q [(size_t)grow * 512 + cc] = h;
                else if (which == 1) Kb[(size_t)grow * 512 + cc] = h;
                else {
                    int b = grow >> 11, m = grow & 2047;
                    Vt[((size_t)b * 512 + cc) * 2048 + m] = h;
                }
            }
        }
    }
}

// ---------------- flash attention with adj mask ----------------
// grid 256: b = blk&7 (XCD affinity), qt = blk>>3. 4 waves x 16 rows, KVB=64.
__global__ __launch_bounds__(256, 1)
void k_attn(const __hip_bfloat16* __restrict__ Q, const __hip_bfloat16* __restrict__ Kg,
            const __hip_bfloat16* __restrict__ Vt, const int* __restrict__ adj,
            __hip_bfloat16* __restrict__ O) {
    __shared__ __hip_bfloat16 Kl[64][520];    // 64 rows x 512 k, pad 8 (2-way banks)
    __shared__ __hip_bfloat16 Vl[512][72];    // 512 d-rows x 64 m, pad 8
    __shared__ __hip_bfloat16 Pl[4][16][72];  // per-wave P relayout buffer
    const int tid = threadIdx.x, lane = tid & 63, w = tid >> 6;
    const int l15 = lane & 15, l4 = lane >> 4;
    const int b = blockIdx.x & 7, qt = blockIdx.x >> 3;
    const float scale = 0.04419417382415922f;  // 1/sqrt(512)

    // Q fragments in registers: wave's 16 rows x 512 k
    bf16x8 qf[16];
    {
        const __hip_bfloat16* qp = Q + ((size_t)b * LSEQ + qt * 64 + w * 16 + l15) * 512;
#pragma unroll
        for (int ks = 0; ks < 16; ++ks)
            qf[ks] = *(const bf16x8*)(qp + ks * 32 + l4 * 8);
    }
    f32x4 acc[32];
#pragma unroll
    for (int n = 0; n < 32; ++n) acc[n] = (f32x4){0.f, 0.f, 0.f, 0.f};
    float m_[4] = {-1e30f, -1e30f, -1e30f, -1e30f};
    float l_[4] = {0.f, 0.f, 0.f, 0.f};

#pragma unroll 1
    for (int kt = 0; kt < 32; ++kt) {
        __syncthreads();
        // stage K tile (64 x 512)
        {
            const __hip_bfloat16* kp = Kg + ((size_t)b * LSEQ + kt * 64) * 512;
#pragma unroll
            for (int i = 0; i < 16; ++i) {
                int c = tid + i * 256;
                int r = c >> 6, o = c & 63;
                bf16x8 v = *(const bf16x8*)(kp + (size_t)r * 512 + o * 8);
                *(bf16x8*)(&Kl[r][o * 8]) = v;
            }
        }
        // stage V tile (512 d x 64 m) from Vt
        {
            const __hip_bfloat16* vp = Vt + (size_t)b * 512 * 2048 + kt * 64;
#pragma unroll
            for (int i = 0; i < 16; ++i) {
                int c = tid + i * 256;
                int r = c >> 3, o = c & 7;
                bf16x8 v = *(const bf16x8*)(vp + (size_t)r * 2048 + o * 8);
                *(bf16x8*)(&Vl[r][o * 8]) = v;
            }
        }
        // adj bits for this wave's 16 rows x 64 cols (prefetch early)
        unsigned amask = 0;
        {
            const int* ap = adj + ((size_t)b * LSEQ + qt * 64 + w * 16 + l4 * 4) * LSEQ + kt * 64 + l15;
#pragma unroll
            for (int r = 0; r < 4; ++r)
#pragma unroll
                for (int n = 0; n < 4; ++n) {
                    int a = ap[(size_t)r * LSEQ + n * 16];
                    amask |= (a != 0 ? 1u : 0u) << (n * 4 + r);
                }
        }
        __syncthreads();
        // scores: S = Q . K^T for wave's 16 rows x 64 keys
        f32x4 sa[4];
#pragma unroll
        for (int n = 0; n < 4; ++n) sa[n] = (f32x4){0.f, 0.f, 0.f, 0.f};
#pragma unroll
        for (int ks = 0; ks < 16; ++ks) {
#pragma unroll
            for (int n = 0; n < 4; ++n) {
                bf16x8 bk = *(const bf16x8*)(&Kl[n * 16 + l15][ks * 32 + l4 * 8]);
                sa[n] = __builtin_amdgcn_mfma_f32_16x16x32_bf16(qf[ks], bk, sa[n], 0, 0, 0);
            }
        }
        // masked row max (across the 16-lane group)
        float mx[4];
#pragma unroll
        for (int r = 0; r < 4; ++r) {
            float v = -1e30f;
#pragma unroll
            for (int n = 0; n < 4; ++n)
                if ((amask >> (n * 4 + r)) & 1) v = fmaxf(v, sa[n][r] * scale);
            v = fmaxf(v, __shfl_xor(v, 1));
            v = fmaxf(v, __shfl_xor(v, 2));
            v = fmaxf(v, __shfl_xor(v, 4));
            v = fmaxf(v, __shfl_xor(v, 8));
            mx[r] = v;
        }
        // deferred-max online softmax update (THR=8)
        float rs[4];
        bool need = false;
#pragma unroll
        for (int r = 0; r < 4; ++r) {
            rs[r] = 1.f;
            if (mx[r] > m_[r] + 8.f) { rs[r] = __expf(m_[r] - mx[r]); m_[r] = mx[r]; }
            l_[r] *= rs[r];
            need |= (rs[r] != 1.f);
        }
        if (need) {
#pragma unroll
            for (int n = 0; n < 32; ++n) {
                acc[n][0] *= rs[0]; acc[n][1] *= rs[1];
                acc[n][2] *= rs[2]; acc[n][3] *= rs[3];
            }
        }
        // p = exp(s - m) (masked -> 0); row sums
#pragma unroll
        for (int n = 0; n < 4; ++n)
#pragma unroll
            for (int r = 0; r < 4; ++r) {
                float p = ((amask >> (n * 4 + r)) & 1) ? __expf(sa[n][r] * scale - m_[r]) : 0.f;
                sa[n][r] = p;
            }
#pragma unroll
        for (int r = 0; r < 4; ++r) {
            float s = sa[0][r] + sa[1][r] + sa[2][r] + sa[3][r];
            s += __shfl_xor(s, 1);
            s += __shfl_xor(s, 2);
            s += __shfl_xor(s, 4);
            s += __shfl_xor(s, 8);
            l_[r] += s;
        }
        // relayout P via per-wave LDS into A-frags
#pragma unroll
        for (int n = 0; n < 4; ++n)
#pragma unroll
            for (int r = 0; r < 4; ++r)
                Pl[w][l4 * 4 + r][n * 16 + l15] = __float2bfloat16(sa[n][r]);
        // PV accumulate: acc += P @ V  (Bt form via Vl)
#pragma unroll
        for (int ks2 = 0; ks2 < 2; ++ks2) {
            bf16x8 pf = *(const bf16x8*)(&Pl[w][l15][ks2 * 32 + l4 * 8]);
#pragma unroll
            for (int n = 0; n < 32; ++n) {
                bf16x8 bv = *(const bf16x8*)(&Vl[n * 16 + l15][ks2 * 32 + l4 * 8]);
                acc[n] = __builtin_amdgcn_mfma_f32_16x16x32_bf16(pf, bv, acc[n], 0, 0, 0);
            }
        }
    }
    // epilogue: O = acc / l
#pragma unroll
    for (int r = 0; r < 4; ++r) {
        float inv = (l_[r] > 0.f) ? 1.f / l_[r] : 0.f;
        size_t row = (size_t)b * LSEQ + qt * 64 + w * 16 + l4 * 4 + r;
#pragma unroll
        for (int n = 0; n < 32; ++n)
            O[row * 512 + n * 16 + l15] = __float2bfloat16(acc[n][r] * inv);
    }
}

// ---------------- out projection + residual + bias -> Y fp32 (into d_out) ----------------
__global__ __launch_bounds__(256, 2)
void k_gemm_out(const __hip_bfloat16* __restrict__ A, const __hip_bfloat16* __restrict__ Bt,
                const float* __restrict__ x, const float* __restrict__ bo,
                float* __restrict__ Y) {
    __shared__ char As[8192], Bs[8192];
    const int tid = threadIdx.x, lane = tid & 63, w = tid >> 6;
    const int l15 = lane & 15, l4 = lane >> 4;
    const int mt = blockIdx.x, nt = blockIdx.y;
    const int wr = (w >> 1) * 64, wc = (w & 1) * 64;
    f32x4 acc[4][4] = {};
    const int c0 = tid, c1 = tid + 256;
    const int r0 = c0 >> 2, o0 = c0 & 3, r1 = c1 >> 2, o1 = c1 & 3;

#pragma unroll 1
    for (int kt = 0; kt < 16; ++kt) {
        __syncthreads();
        bf16x8 a0 = *(const bf16x8*)(A + (size_t)(mt * 128 + r0) * 512 + kt * 32 + o0 * 8);
        bf16x8 a1 = *(const bf16x8*)(A + (size_t)(mt * 128 + r1) * 512 + kt * 32 + o1 * 8);
        bf16x8 b0 = *(const bf16x8*)(Bt + (size_t)(nt * 128 + r0) * 512 + kt * 32 + o0 * 8);
        bf16x8 b1 = *(const bf16x8*)(Bt + (size_t)(nt * 128 + r1) * 512 + kt * 32 + o1 * 8);
        *(bf16x8*)(As + r0 * 64 + ((o0 * 16) ^ ((((r0 >> 1) & 3)) << 4))) = a0;
        *(bf16x8*)(As + r1 * 64 + ((o1 * 16) ^ ((((r1 >> 1) & 3)) << 4))) = a1;
        *(bf16x8*)(Bs + r0 * 64 + ((o0 * 16) ^ ((((r0 >> 1) & 3)) << 4))) = b0;
        *(bf16x8*)(Bs + r1 * 64 + ((o1 * 16) ^ ((((r1 >> 1) & 3)) << 4))) = b1;
        __syncthreads();
        bf16x8 af[4], bfr[4];
#pragma unroll
        for (int i = 0; i < 4; ++i) {
            int r = wr + 16 * i + l15;
            af[i] = *(const bf16x8*)(As + r * 64 + ((16 * l4) ^ ((((r >> 1) & 3)) << 4)));
        }
#pragma unroll
        for (int j = 0; j < 4; ++j) {
            int r = wc + 16 * j + l15;
            bfr[j] = *(const bf16x8*)(Bs + r * 64 + ((16 * l4) ^ ((((r >> 1) & 3)) << 4)));
        }
#pragma unroll
        for (int i = 0; i < 4; ++i)
#pragma unroll
            for (int j = 0; j < 4; ++j)
                acc[i][j] = __builtin_amdgcn_mfma_f32_16x16x32_bf16(af[i], bfr[j], acc[i][j], 0, 0, 0);
    }
#pragma unroll
    for (int i = 0; i < 4; ++i) {
#pragma unroll
        for (int r = 0; r < 4; ++r) {
            size_t grow = (size_t)mt * 128 + wr + 16 * i + (l4 << 2) + r;
#pragma unroll
            for (int j = 0; j < 4; ++j) {
                int gcol = nt * 128 + wc + 16 * j + l15;
                Y[grow * 512 + gcol] = x[grow * 512 + gcol] + acc[i][j][r] + bo[gcol];
            }
        }
    }
}

// ---------------- in-place LayerNorm over rows of 512 ----------------
__global__ void k_ln(float* __restrict__ Y, const float* __restrict__ gamma,
                     const float* __restrict__ beta, float* __restrict__ out) {
    size_t row = blockIdx.x;
    int lane = threadIdx.x;
    float* y = Y + row * 512;
    float4 v0 = *(const float4*)(y + lane * 8);
    float4 v1 = *(const float4*)(y + lane * 8 + 4);
    float s = v0.x + v0.y + v0.z + v0.w + v1.x + v1.y + v1.z + v1.w;
    float q = v0.x * v0.x + v0.y * v0.y + v0.z * v0.z + v0.w * v0.w +
              v1.x * v1.x + v1.y * v1.y + v1.z * v1.z + v1.w * v1.w;
#pragma unroll
    for (int off = 1; off < 64; off <<= 1) {
        s += __shfl_xor(s, off);
        q += __shfl_xor(q, off);
    }
    float mu = s * (1.f / 512.f);
    float var = q * (1.f / 512.f) - mu * mu;
    float rsd = rsqrtf(var + 1e-5f);
    float o[8] = {v0.x, v0.y, v0.z, v0.w, v1.x, v1.y, v1.z, v1.w};
#pragma unroll
    for (int k = 0; k < 8; ++k) {
        int c = lane * 8 + k;
        o[k] = (o[k] - mu) * rsd * gamma[c] + beta[c];
    }
    *(float4*)(out + row * 512 + lane * 8)     = (float4){o[0], o[1], o[2], o[3]};
    *(float4*)(out + row * 512 + lane * 8 + 4) = (float4){o[4], o[5], o[6], o[7]};
}

extern "C" void kernel_launch(void* const* d_in, const int* in_sizes, int n_in,
                              void* d_out, int out_size, void* d_ws, size_t ws_size,
                              hipStream_t stream) {
    const float* x     = (const float*)d_in[0];
    const int*   adj   = (const int*)d_in[1];
    const float* Wq    = (const float*)d_in[2];
    const float* Wk    = (const float*)d_in[3];
    const float* Wv    = (const float*)d_in[4];
    const float* Wo    = (const float*)d_in[5];
    const float* bo    = (const float*)d_in[6];
    const float* gamma = (const float*)d_in[7];
    const float* beta  = (const float*)d_in[8];
    float* out = (float*)d_out;

    // workspace carve (bytes)
    char* ws = (char*)d_ws;
    const size_t SZ_ROWS = (size_t)NBAT * LSEQ;           // 16384
    __hip_bfloat16* xb    = (__hip_bfloat16*)(ws);                       // 16.78 MB (reused as attn-out)
    __hip_bfloat16* Wtqkv = (__hip_bfloat16*)(ws + 16777216);            // 1.57 MB
    __hip_bfloat16* Wto   = (__hip_bfloat16*)(ws + 16777216 + 1572864);  // 0.52 MB
    __hip_bfloat16* Qb    = (__hip_bfloat16*)(ws + 18874368);            // 16.78 MB
    __hip_bfloat16* Kb    = (__hip_bfloat16*)(ws + 18874368 + 16777216);
    __hip_bfloat16* Vtb   = (__hip_bfloat16*)(ws + 18874368 + 2 * 16777216);
    __hip_bfloat16* Ab    = xb;  // attention output aliases xb (xb dead after QKV GEMM)
    (void)in_sizes; (void)n_in; (void)out_size; (void)ws_size;

    k_cvt_x<<<(SZ_ROWS * DDIM) / (256 * 4), 256, 0, stream>>>(x, xb);
    k_cvt_w<<<1024, 256, 0, stream>>>(Wq, Wk, Wv, Wo, Wtqkv, Wto);
    k_gemm_qkv<<<dim3(128, 12), 256, 0, stream>>>(xb, Wtqkv, Qb, Kb, Vtb);
    k_attn<<<256, 256, 0, stream>>>(Qb, Kb, Vtb, adj, Ab);
    k_gemm_out<<<dim3(128, 4), 256, 0, stream>>>(Ab, Wto, x, bo, out);
    k_ln<<<(unsigned)SZ_ROWS, 64, 0, stream>>>(out, gamma, beta, out);
}